// Round 2
// baseline (482.550 us; speedup 1.0000x reference)
//
#include <hip/hip_runtime.h>
#include <stdint.h>
#include <stddef.h>

// Problem constants
constexpr int B_ = 16, N_ = 8, C_ = 3, H_ = 48, W_ = 48, K_ = 5, NK_ = 4;
constexpr int HW_ = H_ * W_;            // 2304
constexpr int IMGS_ = B_ * N_;          // 128
constexpr int PW_ = W_ + 4;             // 52 (padded width)
constexpr int PH_ = H_ + 4;             // 52
constexpr int PHW_ = PH_ * PW_;         // 2704
constexpr int HWH_ = HW_ / 2;           // 1152 pixel-pairs per [H,W] plane

// Kernel 1: padded channel-sum of frames: cs[img][52][52] (fp32), zero border.
__global__ void kcs(const float* __restrict__ frames, float* __restrict__ cs) {
    int id = blockIdx.x * blockDim.x + threadIdx.x;
    if (id >= IMGS_ * PHW_) return;
    int img = id / PHW_;
    int rem = id - img * PHW_;
    int ph = rem / PW_;
    int pw = rem - ph * PW_;
    int h = ph - 2, w = pw - 2;
    float s = 0.f;
    if ((unsigned)h < (unsigned)H_ && (unsigned)w < (unsigned)W_) {
        const float* f = frames + (size_t)img * (C_ * HW_) + h * W_ + w;
        s = f[0] + f[HW_] + f[2 * HW_];
    }
    cs[id] = s;
}

// Kernel 2: main fused conv. One thread = 2 adjacent pixels along w.
// pred_i[c] = 0.25 * sum_g kw[g,c] * sum_k core[g*75+k*3+c] * fs[di][dj]
__global__ __launch_bounds__(64) void kmain(const float* __restrict__ core,
                                            const float* __restrict__ kw,
                                            const float* __restrict__ cs,
                                            float* __restrict__ out) {
    int tid = blockIdx.x * 64 + threadIdx.x;
    int img = tid / HWH_;                 // 1152 threads per (b,n) image
    int r = tid - img * HWH_;
    int h = r / (W_ / 2);
    int wg = r - h * (W_ / 2);
    int w0 = wg * 2;
    int pix0 = h * W_ + w0;

    // 5x6 channel-sum tile (padded coords: rows h..h+4, cols w0..w0+5)
    float fs[5][6];
    const float* csp = cs + img * PHW_ + h * PW_ + w0;
#pragma unroll
    for (int rr = 0; rr < 5; ++rr) {
        const float2* rp = (const float2*)(csp + rr * PW_);
        float2 a = rp[0], b = rp[1], c = rp[2];
        fs[rr][0] = a.x; fs[rr][1] = a.y;
        fs[rr][2] = b.x; fs[rr][3] = b.y;
        fs[rr][4] = c.x; fs[rr][5] = c.y;
    }

    const float* cp = core + (size_t)img * (300 * HW_) + pix0;
    const float* kp = kw + (size_t)img * (12 * HW_) + pix0;

    float p0[3] = {0.f, 0.f, 0.f};
    float p1[3] = {0.f, 0.f, 0.f};
    for (int g = 0; g < 4; ++g) {
#pragma unroll
        for (int c = 0; c < 3; ++c) {
            float t0 = 0.f, t1 = 0.f;
            const float* cpk = cp + (size_t)(g * 75 + c) * HW_;
#pragma unroll
            for (int k = 0; k < 25; ++k) {
                float2 d = *(const float2*)(cpk + (size_t)(k * 3) * HW_);
                int di = k / 5, dj = k - di * 5;
                t0 += d.x * fs[di][dj];
                t1 += d.y * fs[di][dj + 1];
            }
            float2 kd = *(const float2*)(kp + (size_t)(g * 3 + c) * HW_);
            p0[c] += kd.x * t0;
            p1[c] += kd.y * t1;
        }
    }

    float* op = out + (size_t)img * (3 * HW_) + pix0;
#pragma unroll
    for (int c = 0; c < 3; ++c) {
        float2 v = make_float2(0.25f * p0[c], 0.25f * p1[c]);
        *(float2*)(op + (size_t)c * HW_) = v;
    }
}

// Kernel 3: pred_img[b,c,h,w] = mean over n of pred_img_i
__global__ void kmean(const float* __restrict__ outi, float* __restrict__ outm) {
    int id = blockIdx.x * blockDim.x + threadIdx.x;
    if (id >= B_ * 3 * HW_) return;
    int b = id / (3 * HW_);
    int rem = id - b * (3 * HW_);
    const float* p = outi + (size_t)b * (N_ * 3 * HW_) + rem;
    float s = 0.f;
#pragma unroll
    for (int n = 0; n < N_; ++n) s += p[(size_t)n * 3 * HW_];
    outm[id] = s * 0.125f;
}

extern "C" void kernel_launch(void* const* d_in, const int* in_sizes, int n_in,
                              void* d_out, int out_size, void* d_ws, size_t ws_size,
                              hipStream_t stream) {
    const float* frames = (const float*)d_in[0];   // [B,N,3,H,W]
    const float* core = (const float*)d_in[1];     // [B,N,300,H,W] (flat middle dims)
    const float* kw = (const float*)d_in[2];       // [B,N,4,3,H,W]
    float* cs = (float*)d_ws;                      // 128*52*52 fp32 = 1.38 MB
    float* outi = (float*)d_out;                   // pred_img_i: [B,N,3,H,W]
    float* outm = outi + (size_t)B_ * N_ * 3 * HW_; // pred_img: [B,3,H,W]

    kcs<<<(IMGS_ * PHW_ + 255) / 256, 256, 0, stream>>>(frames, cs);
    kmain<<<IMGS_ * HWH_ / 64, 64, 0, stream>>>(core, kw, cs, outi);
    kmean<<<(B_ * 3 * HW_ + 255) / 256, 256, 0, stream>>>(outi, outm);
}